// Round 1
// 4222.591 us; speedup vs baseline: 1.3582x; 1.3582x over previous
//
#include <hip/hip_runtime.h>

#define BB 64
#define TT 4995
#define VV 4096
#define EE 100
#define UU 64
#define U3 192

// Static device workspace: embW[v][k] = (emb @ W1 + b1[0])[v][k], 3.07 MB.
__device__ float g_embW[VV * U3];

__device__ __forceinline__ float fast_sigmoid(float x) {
    return __builtin_amdgcn_rcpf(1.0f + __expf(-x));
}
__device__ __forceinline__ float fast_tanh(float x) {
    return __builtin_amdgcn_rcpf(1.0f + __expf(-2.0f * x)) * 2.0f - 1.0f;
}

// Kernel A: embW[v][k] = sum_j emb[v][j] * W1[j][k] + b1[0][k]
__global__ void gru_embw_kernel(const float* __restrict__ emb,
                                const float* __restrict__ W1,
                                const float* __restrict__ b1) {
    __shared__ float row[EE];
    const int v = blockIdx.x;
    const int k = threadIdx.x;  // 0..191
    if (k < EE) row[k] = emb[v * EE + k];
    __syncthreads();
    float acc = b1[k];
    #pragma unroll 4
    for (int j = 0; j < EE; ++j)
        acc = fmaf(row[j], W1[j * U3 + k], acc);
    g_embW[v * U3 + k] = acc;
}

// Kernel B: software-pipelined fused 2-layer GRU scan.
// Loop invariant at top of step s: h1 = a1(s-1), h2 = b2(s-2).
// Each step computes h1(s) [layer1 on x(s)] and h2(s-1) [layer2 on h1(s-1)]
// CONCURRENTLY — they only depend on state available at loop top.
// Every thread does all 3 length-64 dots (3 independent FMA chains), then
// one barrier, wave0 updates h1 / wave1 updates h2 in parallel, one barrier.
__global__ __launch_bounds__(192, 1)
void gru_scan_kernel(const int* __restrict__ tokens,
                     const float* __restrict__ U1,
                     const float* __restrict__ b1,
                     const float* __restrict__ W2,
                     const float* __restrict__ U2,
                     const float* __restrict__ b2,
                     const float* __restrict__ Wout,
                     const float* __restrict__ bout,
                     float* __restrict__ out) {
    const int b = blockIdx.x;
    const int k = threadIdx.x;  // 0..191
    const int wv = k >> 6;      // wave id: 0,1,2 (branches are wave-uniform)
    const int u  = k & 63;

    __shared__ __align__(16) float h1[UU];
    __shared__ __align__(16) float h2[UU];
    // gate pre-activation exchange buffers (separate arrays: stride-4B
    // consecutive per lane -> conflict-free)
    __shared__ float L1z[UU], L1r[UU], L1xh[UU], L1hph[UU];
    __shared__ float L2z[UU], L2r[UU], L2xh[UU], L2hph[UU];

    // Per-thread weight columns (statically indexed -> registers/AGPRs)
    float u1c[UU], w2c[UU], u2c[UU];
    #pragma unroll
    for (int j = 0; j < UU; ++j) {
        u1c[j] = U1[j * U3 + k];
        w2c[j] = W2[j * U3 + k];
        u2c[j] = U2[j * U3 + k];
    }
    const float bu1 = b1[U3 + k];   // b1 row 1 (recurrent bias)
    const float b20 = b2[k];        // b2 row 0 (input bias, layer 2)
    const float b21 = b2[U3 + k];   // b2 row 1 (recurrent bias, layer 2)

    if (k < UU) { h1[k] = 0.0f; h2[k] = 0.0f; }
    __syncthreads();

    const int* tokb = tokens + b * TT;
    int tok1 = tokb[1];
    float xk = g_embW[(long)tokb[0] * U3 + k];  // xp1 col k for s=0

    // s = 0..TT inclusive: s<TT does layer1 on x(s); s>0 does layer2 on
    // h1 from the previous step. 4996 iterations total.
    for (int s = 0; s <= TT; ++s) {
        // prefetch next step's token + embW row (hides L2 latency)
        const int tnn = (s + 2 < TT) ? (s + 2) : (TT - 1);
        const int tok_nn = tokb[tnn];
        const float xk_next = g_embW[(long)tok1 * U3 + k];

        // ---- dot phase: 3 independent length-64 dots per thread,
        //      streamed from broadcast float4 LDS reads ----
        float acc1 = bu1;   // h1 . U1[:,k]   (layer1 recurrent)
        float accx = b20;   // h1 . W2[:,k]   (layer2 input proj)
        float acch = b21;   // h2 . U2[:,k]   (layer2 recurrent)
        #pragma unroll
        for (int j4 = 0; j4 < UU / 4; ++j4) {
            const float4 a4 = ((const float4*)h1)[j4];
            const float4 c4 = ((const float4*)h2)[j4];
            acc1 = fmaf(a4.x, u1c[4 * j4 + 0], acc1);
            acc1 = fmaf(a4.y, u1c[4 * j4 + 1], acc1);
            acc1 = fmaf(a4.z, u1c[4 * j4 + 2], acc1);
            acc1 = fmaf(a4.w, u1c[4 * j4 + 3], acc1);
            accx = fmaf(a4.x, w2c[4 * j4 + 0], accx);
            accx = fmaf(a4.y, w2c[4 * j4 + 1], accx);
            accx = fmaf(a4.z, w2c[4 * j4 + 2], accx);
            accx = fmaf(a4.w, w2c[4 * j4 + 3], accx);
            acch = fmaf(c4.x, u2c[4 * j4 + 0], acch);
            acch = fmaf(c4.y, u2c[4 * j4 + 1], acch);
            acch = fmaf(c4.z, u2c[4 * j4 + 2], acch);
            acch = fmaf(c4.w, u2c[4 * j4 + 3], acch);
        }

        // ---- gate-share phase (wave-uniform role split) ----
        if (wv == 0) {
            L1z[u] = fast_sigmoid(xk + acc1);
            L2z[u] = fast_sigmoid(accx + acch);
        } else if (wv == 1) {
            L1r[u] = fast_sigmoid(xk + acc1);
            L2r[u] = fast_sigmoid(accx + acch);
        } else {
            L1xh[u]  = xk;   L1hph[u] = acc1;
            L2xh[u]  = accx; L2hph[u] = acch;
        }
        __syncthreads();

        // ---- update phase: wave0 -> h1, wave1 -> h2, concurrent ----
        if (wv == 0) {
            if (s < TT) {
                const float z  = L1z[u];
                const float hh = fast_tanh(L1xh[u] + L1r[u] * L1hph[u]);
                h1[u] = z * h1[u] + (1.0f - z) * hh;
            }
        } else if (wv == 1) {
            if (s > 0) {
                const float z  = L2z[u];
                const float hh = fast_tanh(L2xh[u] + L2r[u] * L2hph[u]);
                h2[u] = z * h2[u] + (1.0f - z) * hh;
            }
        }
        __syncthreads();

        // rotate prefetch pipeline
        xk = xk_next;
        tok1 = tok_nn;
    }

    // ---- output head: out[b] = sigmoid(dot(h2, Wout) + bout) ----
    if (k == 0) {
        float s = 0.0f;
        #pragma unroll 4
        for (int j = 0; j < UU; ++j) s = fmaf(h2[j], Wout[j], s);
        out[b] = fast_sigmoid(s + bout[0]);
    }
}

extern "C" void kernel_launch(void* const* d_in, const int* in_sizes, int n_in,
                              void* d_out, int out_size, void* d_ws, size_t ws_size,
                              hipStream_t stream) {
    const int*   tokens = (const int*)  d_in[0];
    const float* emb    = (const float*)d_in[1];
    const float* W1     = (const float*)d_in[2];
    const float* U1w    = (const float*)d_in[3];
    const float* b1     = (const float*)d_in[4];
    const float* W2     = (const float*)d_in[5];
    const float* U2w    = (const float*)d_in[6];
    const float* b2     = (const float*)d_in[7];
    const float* Wout   = (const float*)d_in[8];
    const float* bout   = (const float*)d_in[9];
    float* out = (float*)d_out;

    gru_embw_kernel<<<VV, 192, 0, stream>>>(emb, W1, b1);
    gru_scan_kernel<<<BB, 192, 0, stream>>>(tokens, U1w, b1, W2, U2w,
                                            b2, Wout, bout, out);
}

// Round 3
// 3269.290 us; speedup vs baseline: 1.7543x; 1.2916x over previous
//
#include <hip/hip_runtime.h>

#define BB 64
#define TT 4995
#define VV 4096
#define EE 100
#define UU 64
#define U3 192
#define BPB 16            // batch rows per block
#define NBLK (BB / BPB)   // 4 blocks

using bf16x8 = __attribute__((ext_vector_type(8))) short;
using f32x4  = __attribute__((ext_vector_type(4))) float;

#define MFMA16 __builtin_amdgcn_mfma_f32_16x16x32_bf16

// Static device workspace: embW[v][k] = (emb @ W1 + b1[0])[v][k], 3.07 MB (L2-resident).
__device__ float g_embW[VV * U3];

__device__ __forceinline__ float fast_sigmoid(float x) {
    return __builtin_amdgcn_rcpf(1.0f + __expf(-x));
}
__device__ __forceinline__ float fast_tanh(float x) {
    return __builtin_amdgcn_rcpf(1.0f + __expf(-2.0f * x)) * 2.0f - 1.0f;
}
// f32 -> bf16 round-to-nearest-even
__device__ __forceinline__ unsigned short f2bf(float f) {
    unsigned u = __float_as_uint(f);
    return (unsigned short)((u + 0x7FFFu + ((u >> 16) & 1u)) >> 16);
}
__device__ __forceinline__ float bf2f(unsigned short h) {
    return __uint_as_float(((unsigned)h) << 16);
}

// Kernel A: embW[v][k] = sum_j emb[v][j] * W1[j][k] + b1[0][k]  (fp32 table)
__global__ void gru_embw_kernel(const float* __restrict__ emb,
                                const float* __restrict__ W1,
                                const float* __restrict__ b1) {
    __shared__ float row[EE];
    const int v = blockIdx.x;
    const int k = threadIdx.x;  // 0..191
    if (k < EE) row[k] = emb[v * EE + k];
    __syncthreads();
    float acc = b1[k];
    #pragma unroll 4
    for (int j = 0; j < EE; ++j)
        acc = fmaf(row[j], W1[j * U3 + k], acc);
    g_embW[v * U3 + k] = acc;
}

// Kernel B: MFMA-based fused 2-layer GRU scan.
// 4 blocks x 16 batch rows; 8 waves: waves 0-3 = layer1 unit-tile w,
// waves 4-7 = layer2 unit-tile w-4. Weights live in registers as MFMA
// B-fragments (loop-invariant). h1/h2 cross steps via XOR-swizzled bf16 LDS
// (double-buffered -> ONE barrier per step). Layer2 lags layer1 by one step
// (same software pipeline as before), so both layers share the h1(s-1)
// A-fragments each step.
__global__ __launch_bounds__(512, 1)
void gru_scan_kernel(const int* __restrict__ tokens,
                     const float* __restrict__ U1,
                     const float* __restrict__ b1,
                     const float* __restrict__ W2,
                     const float* __restrict__ U2,
                     const float* __restrict__ b2,
                     const float* __restrict__ Wout,
                     const float* __restrict__ bout,
                     float* __restrict__ out) {
    const int blk  = blockIdx.x;
    const int tid  = threadIdx.x;
    const int wave = tid >> 6;
    const int lane = tid & 63;
    const int lg   = lane >> 4;   // 0..3 (k-chunk group)
    const int lc   = lane & 15;   // 0..15 (A-row / D-col)
    const bool isL2 = (wave >= 4);
    const int ut   = wave & 3;    // unit tile (16 units) this wave owns

    // h state: [buf(2)][which(2: h1,h2)][row 16][unit 64] bf16, XOR-swizzled:
    // byte = ((buf*2+which)*16 + row)*128 + ((unit*2) ^ ((row&7)<<4))
    __shared__ __align__(16) char hls[8192];
    for (int i = tid; i < 2048; i += 512) ((int*)hls)[i] = 0;

    // ---- weight B-fragments (once). k-map: k = 8*lg + 32*kk + e.
    // A uses the same k-map, so any HW k-permutation cancels (A/B mirrored).
    bf16x8 fb[12];
    const int cz = ut * 16 + lc;          // z gate column
    const int cr = 64 + ut * 16 + lc;     // r gate column
    const int ch = 128 + ut * 16 + lc;    // hh gate column
    {
        const float* M0 = isL2 ? W2 : U1;
        #pragma unroll
        for (int g = 0; g < 3; ++g) {
            const int col = g * 64 + ut * 16 + lc;
            #pragma unroll
            for (int kk = 0; kk < 2; ++kk) {
                bf16x8 v;
                #pragma unroll
                for (int e = 0; e < 8; ++e)
                    v[e] = (short)f2bf(M0[(8 * lg + 32 * kk + e) * U3 + col]);
                fb[g * 2 + kk] = v;
            }
        }
        if (isL2) {
            #pragma unroll
            for (int g = 0; g < 3; ++g) {
                const int col = g * 64 + ut * 16 + lc;
                #pragma unroll
                for (int kk = 0; kk < 2; ++kk) {
                    bf16x8 v;
                    #pragma unroll
                    for (int e = 0; e < 8; ++e)
                        v[e] = (short)f2bf(U2[(8 * lg + 32 * kk + e) * U3 + col]);
                    fb[6 + g * 2 + kk] = v;
                }
            }
        } else {
            #pragma unroll
            for (int q = 6; q < 12; ++q) fb[q] = fb[q - 6];  // keep defined
        }
    }

    // biases (per-column, constant over rows)
    float bias_z, bias_r, bias_h, bias_h2 = 0.0f;
    if (!isL2) {
        bias_z = b1[U3 + cz]; bias_r = b1[U3 + cr]; bias_h = b1[U3 + ch];
    } else {
        bias_z  = b2[cz] + b2[U3 + cz];
        bias_r  = b2[cr] + b2[U3 + cr];
        bias_h  = b2[ch];         // xh accumulator init (input-side bias)
        bias_h2 = b2[U3 + ch];    // hph accumulator init (recurrent bias)
    }

    // ---- xp/token prefetch pipeline (L1 waves). Static 2-deep rotation via
    // compile-time half index (no runtime-indexed arrays -> stays in regs).
    float xp[2][12];
    int   tok[2][4];
    if (!isL2) {
        #pragma unroll
        for (int r = 0; r < 4; ++r) {
            const int rb = (blk * BPB + 4 * lg + r) * TT;
            const int t0 = tokens[rb];
            tok[0][r] = tokens[rb + 1];
            tok[1][r] = tokens[rb + 2];
            xp[0][r]     = g_embW[t0 * U3 + cz];
            xp[0][4 + r] = g_embW[t0 * U3 + cr];
            xp[0][8 + r] = g_embW[t0 * U3 + ch];
        }
    }

    f32x4 h1o = {0.f, 0.f, 0.f, 0.f};   // h1(s-1) in D layout (L1 waves)
    f32x4 h2o = {0.f, 0.f, 0.f, 0.f};   // h2(s-2) in D layout (L2 waves)

    __syncthreads();

    const int swzA = (lc & 7) << 4;     // A-read row swizzle (row = lc)

    #pragma unroll 1
    for (int sb = 0; sb < TT + 1; sb += 2) {      // TT+1 = 4996 steps total
        #pragma unroll
        for (int half = 0; half < 2; ++half) {
            const int s = sb + half;              // step; pb = half
            char* rdb = hls + half * 4096;        // read buffer
            char* wrb = hls + (half ^ 1) * 4096;  // write buffer

            // A-fragments: rows=batch (lc), k=units. One ds_read_b128 each.
            bf16x8 a1_0 = *(const bf16x8*)(rdb + lc * 128 + ((16 * lg) ^ swzA));
            bf16x8 a1_1 = *(const bf16x8*)(rdb + lc * 128 + ((16 * lg + 64) ^ swzA));
            bf16x8 a2_0 = *(const bf16x8*)(rdb + 2048 + lc * 128 + ((16 * lg) ^ swzA));
            bf16x8 a2_1 = *(const bf16x8*)(rdb + 2048 + lc * 128 + ((16 * lg + 64) ^ swzA));

            if (!isL2) {
                // prefetch xp for step s+1 (uses tok[half] = tokens[s+1]),
                // and tokens for s+2 into tok[half^1]
                #pragma unroll
                for (int r = 0; r < 4; ++r) {
                    const int tn = tok[half][r];
                    xp[half ^ 1][r]     = g_embW[tn * U3 + cz];
                    xp[half ^ 1][4 + r] = g_embW[tn * U3 + cr];
                    xp[half ^ 1][8 + r] = g_embW[tn * U3 + ch];
                }
                const int s2 = (s + 2 < TT) ? (s + 2) : (TT - 1);
                #pragma unroll
                for (int r = 0; r < 4; ++r)
                    tok[half ^ 1][r] = tokens[(blk * BPB + 4 * lg + r) * TT + s2];

                if (s < TT) {   // layer 1 computes h1(s)
                    f32x4 az = {bias_z, bias_z, bias_z, bias_z};
                    f32x4 ar = {bias_r, bias_r, bias_r, bias_r};
                    f32x4 ah = {bias_h, bias_h, bias_h, bias_h};
                    az = MFMA16(a1_0, fb[0], az, 0, 0, 0);
                    az = MFMA16(a1_1, fb[1], az, 0, 0, 0);
                    ar = MFMA16(a1_0, fb[2], ar, 0, 0, 0);
                    ar = MFMA16(a1_1, fb[3], ar, 0, 0, 0);
                    ah = MFMA16(a1_0, fb[4], ah, 0, 0, 0);
                    ah = MFMA16(a1_1, fb[5], ah, 0, 0, 0);
                    f32x4 h1n;
                    #pragma unroll
                    for (int r = 0; r < 4; ++r) {
                        const float z  = fast_sigmoid(xp[half][r]     + az[r]);
                        const float rg = fast_sigmoid(xp[half][4 + r] + ar[r]);
                        const float hh = fast_tanh(xp[half][8 + r] + rg * ah[r]);
                        h1n[r] = z * h1o[r] + (1.0f - z) * hh;
                    }
                    h1o = h1n;
                    #pragma unroll
                    for (int r = 0; r < 4; ++r) {
                        const int row = 4 * lg + r;
                        *(unsigned short*)(wrb + row * 128 +
                            (((ut * 16 + lc) * 2) ^ ((row & 7) << 4))) = f2bf(h1n[r]);
                    }
                }
            } else {
                if (s > 0) {    // layer 2 computes h2(s-1)
                    f32x4 az = {bias_z,  bias_z,  bias_z,  bias_z };
                    f32x4 ar = {bias_r,  bias_r,  bias_r,  bias_r };
                    f32x4 ax = {bias_h,  bias_h,  bias_h,  bias_h };
                    f32x4 ap = {bias_h2, bias_h2, bias_h2, bias_h2};
                    az = MFMA16(a1_0, fb[0],  az, 0, 0, 0);   // h1@W2 (z)
                    az = MFMA16(a1_1, fb[1],  az, 0, 0, 0);
                    az = MFMA16(a2_0, fb[6],  az, 0, 0, 0);   // + h2@U2 (z)
                    az = MFMA16(a2_1, fb[7],  az, 0, 0, 0);
                    ar = MFMA16(a1_0, fb[2],  ar, 0, 0, 0);
                    ar = MFMA16(a1_1, fb[3],  ar, 0, 0, 0);
                    ar = MFMA16(a2_0, fb[8],  ar, 0, 0, 0);
                    ar = MFMA16(a2_1, fb[9],  ar, 0, 0, 0);
                    ax = MFMA16(a1_0, fb[4],  ax, 0, 0, 0);   // xh (input side)
                    ax = MFMA16(a1_1, fb[5],  ax, 0, 0, 0);
                    ap = MFMA16(a2_0, fb[10], ap, 0, 0, 0);   // hph (recurrent)
                    ap = MFMA16(a2_1, fb[11], ap, 0, 0, 0);
                    f32x4 h2n;
                    #pragma unroll
                    for (int r = 0; r < 4; ++r) {
                        const float z  = fast_sigmoid(az[r]);
                        const float rg = fast_sigmoid(ar[r]);
                        const float hh = fast_tanh(ax[r] + rg * ap[r]);
                        h2n[r] = z * h2o[r] + (1.0f - z) * hh;
                    }
                    h2o = h2n;
                    #pragma unroll
                    for (int r = 0; r < 4; ++r) {
                        const int row = 4 * lg + r;
                        *(unsigned short*)(wrb + 2048 + row * 128 +
                            (((ut * 16 + lc) * 2) ^ ((row & 7) << 4))) = f2bf(h2n[r]);
                    }
                }
            }
            __syncthreads();
        }
    }

    // ---- output head: h2(TT-1) sits in buf0/which=1 (step TT wrote buf0) ----
    if (wave == 0 && lane < 16) {
        float acc = bout[0];
        #pragma unroll 8
        for (int u = 0; u < UU; ++u) {
            const unsigned short hv = *(const unsigned short*)(hls + 2048 +
                lane * 128 + ((u * 2) ^ ((lane & 7) << 4)));
            acc = fmaf(bf2f(hv), Wout[u], acc);
        }
        out[blk * BPB + lane] = fast_sigmoid(acc);
    }
}

extern "C" void kernel_launch(void* const* d_in, const int* in_sizes, int n_in,
                              void* d_out, int out_size, void* d_ws, size_t ws_size,
                              hipStream_t stream) {
    const int*   tokens = (const int*)  d_in[0];
    const float* emb    = (const float*)d_in[1];
    const float* W1     = (const float*)d_in[2];
    const float* U1w    = (const float*)d_in[3];
    const float* b1     = (const float*)d_in[4];
    const float* W2     = (const float*)d_in[5];
    const float* U2w    = (const float*)d_in[6];
    const float* b2     = (const float*)d_in[7];
    const float* Wout   = (const float*)d_in[8];
    const float* bout   = (const float*)d_in[9];
    float* out = (float*)d_out;

    gru_embw_kernel<<<VV, 192, 0, stream>>>(emb, W1, b1);
    gru_scan_kernel<<<NBLK, 512, 0, stream>>>(tokens, U1w, b1, W2, U2w,
                                              b2, Wout, bout, out);
}

// Round 4
// 1609.409 us; speedup vs baseline: 3.5636x; 2.0314x over previous
//
#include <hip/hip_runtime.h>

#define BB 64
#define TT 4995
#define VV 4096
#define EE 100
#define UU 64
#define U3 192
#define BPB 4             // batch rows per block (spread across D lane-groups)
#define NBLK (BB / BPB)   // 16 blocks

using bf16x8 = __attribute__((ext_vector_type(8))) short;
using f32x4  = __attribute__((ext_vector_type(4))) float;

#define MFMA16 __builtin_amdgcn_mfma_f32_16x16x32_bf16

// Static device workspace: embW[v][k] = (emb @ W1 + b1[0])[v][k], 3.07 MB (L2-resident).
__device__ float g_embW[VV * U3];

__device__ __forceinline__ float fast_sigmoid(float x) {
    return __builtin_amdgcn_rcpf(1.0f + __expf(-x));
}
__device__ __forceinline__ float fast_tanh(float x) {
    return __builtin_amdgcn_rcpf(1.0f + __expf(-2.0f * x)) * 2.0f - 1.0f;
}
// f32 -> bf16 round-to-nearest-even
__device__ __forceinline__ unsigned short f2bf(float f) {
    unsigned u = __float_as_uint(f);
    return (unsigned short)((u + 0x7FFFu + ((u >> 16) & 1u)) >> 16);
}
__device__ __forceinline__ float bf2f(unsigned short h) {
    return __uint_as_float(((unsigned)h) << 16);
}

// Kernel A: embW[v][k] = sum_j emb[v][j] * W1[j][k] + b1[0][k]  (fp32 table)
__global__ void gru_embw_kernel(const float* __restrict__ emb,
                                const float* __restrict__ W1,
                                const float* __restrict__ b1) {
    __shared__ float row[EE];
    const int v = blockIdx.x;
    const int k = threadIdx.x;  // 0..191
    if (k < EE) row[k] = emb[v * EE + k];
    __syncthreads();
    float acc = b1[k];
    #pragma unroll 4
    for (int j = 0; j < EE; ++j)
        acc = fmaf(row[j], W1[j * U3 + k], acc);
    g_embW[v * U3 + k] = acc;
}

// Kernel B: MFMA-based fused 2-layer GRU scan, 16 blocks x 4 batch rows.
// Batch row rb (0..3) lives at MFMA/LDS row 4*rb, so in the D layout
// (col=lane&15, row=(lane>>4)*4+reg) every lane owns EXACTLY ONE valid
// (row,unit) at reg 0 -> one gate computation per lane per step (was 4).
// Waves 0-3 = layer1 unit-tile ut, waves 4-7 = layer2 unit-tile ut.
// Weights persist in registers as B-fragments; h-state crosses steps via
// XOR-swizzled bf16 LDS (double-buffered, ONE barrier/step). Layer2 lags
// layer1 by one step (same software pipeline as R1-R3).
__global__ __launch_bounds__(512, 1)
void gru_scan_kernel(const int* __restrict__ tokens,
                     const float* __restrict__ U1,
                     const float* __restrict__ b1,
                     const float* __restrict__ W2,
                     const float* __restrict__ U2,
                     const float* __restrict__ b2,
                     const float* __restrict__ Wout,
                     const float* __restrict__ bout,
                     float* __restrict__ out) {
    const int blk  = blockIdx.x;
    const int tid  = threadIdx.x;
    const int wave = tid >> 6;
    const int lane = tid & 63;
    const int lg   = lane >> 4;   // 0..3: k-chunk group (A/B), row group (D)
    const int lc   = lane & 15;   // 0..15: A-row / D-col
    const bool isL2 = (wave >= 4);
    const int ut   = wave & 3;    // unit tile (16 units) this wave owns

    // h state: [buf(2)][which(2: h1,h2)][row 16][unit 64] bf16, XOR-swizzled:
    // byte = ((buf*2+which)*16 + row)*128 + ((unit*2) ^ ((row&7)<<4))
    // Rows != 0,4,8,12 are never written -> stay zero (harmless in MFMA).
    __shared__ __align__(16) char hls[8192];
    for (int i = tid; i < 2048; i += 512) ((int*)hls)[i] = 0;

    // ---- weight B-fragments (once). k-map: k = 8*lg + 32*kk + e.
    // A uses the same k-map, so any HW k-permutation cancels (A/B mirrored).
    bf16x8 fb[12];
    const int cz = ut * 16 + lc;          // z gate column
    const int cr = 64 + ut * 16 + lc;     // r gate column
    const int ch = 128 + ut * 16 + lc;    // hh gate column
    {
        const float* M0 = isL2 ? W2 : U1;
        #pragma unroll
        for (int g = 0; g < 3; ++g) {
            const int col = g * 64 + ut * 16 + lc;
            #pragma unroll
            for (int kk = 0; kk < 2; ++kk) {
                bf16x8 v;
                #pragma unroll
                for (int e = 0; e < 8; ++e)
                    v[e] = (short)f2bf(M0[(8 * lg + 32 * kk + e) * U3 + col]);
                fb[g * 2 + kk] = v;
            }
        }
        if (isL2) {
            #pragma unroll
            for (int g = 0; g < 3; ++g) {
                const int col = g * 64 + ut * 16 + lc;
                #pragma unroll
                for (int kk = 0; kk < 2; ++kk) {
                    bf16x8 v;
                    #pragma unroll
                    for (int e = 0; e < 8; ++e)
                        v[e] = (short)f2bf(U2[(8 * lg + 32 * kk + e) * U3 + col]);
                    fb[6 + g * 2 + kk] = v;
                }
            }
        } else {
            #pragma unroll
            for (int q = 6; q < 12; ++q) fb[q] = fb[q - 6];  // keep defined
        }
    }

    // biases (per-column, constant over rows)
    float bias_z, bias_r, bias_h, bias_h2 = 0.0f;
    if (!isL2) {
        bias_z = b1[U3 + cz]; bias_r = b1[U3 + cr]; bias_h = b1[U3 + ch];
    } else {
        bias_z  = b2[cz] + b2[U3 + cz];
        bias_r  = b2[cr] + b2[U3 + cr];
        bias_h  = b2[ch];         // xh accumulator init (input-side bias)
        bias_h2 = b2[U3 + ch];    // hph accumulator init (recurrent bias)
    }

    // ---- xp/token prefetch pipeline (L1 waves). Each lane serves its ONE
    // batch row (rb = lg): 3 embW floats + 1 token per step. Static 2-deep
    // rotation via compile-time half index (stays in registers).
    float xp[2][3];
    int   tok[2];
    const int rowbase = (blk * BPB + lg) * TT;   // this lane's token row
    if (!isL2) {
        const int t0 = tokens[rowbase];
        tok[0] = tokens[rowbase + 1];
        tok[1] = tokens[rowbase + 2];
        xp[0][0] = g_embW[t0 * U3 + cz];
        xp[0][1] = g_embW[t0 * U3 + cr];
        xp[0][2] = g_embW[t0 * U3 + ch];
    }

    float h1o = 0.0f;   // h1(s-1)[row 4*lg, col cz] master copy (L1 waves)
    float h2o = 0.0f;   // h2(s-2) master copy (L2 waves)

    __syncthreads();

    const int swzA = (lc & 7) << 4;              // A-read row swizzle (row = lc)
    const int myrow = 4 * lg;                    // this lane's MFMA/LDS row
    const int wswz  = ((myrow & 7) << 4);        // write swizzle for that row
    const int wbyte = myrow * 128 + (((ut * 16 + lc) * 2) ^ wswz);

    #pragma unroll 1
    for (int sb = 0; sb < TT + 1; sb += 2) {      // TT+1 = 4996 steps total
        #pragma unroll
        for (int half = 0; half < 2; ++half) {
            const int s = sb + half;              // step
            char* rdb = hls + half * 4096;        // read buffer
            char* wrb = hls + (half ^ 1) * 4096;  // write buffer

            // A-fragments: rows=batch (lc), k=units. One ds_read_b128 each.
            bf16x8 a1_0 = *(const bf16x8*)(rdb + lc * 128 + ((16 * lg) ^ swzA));
            bf16x8 a1_1 = *(const bf16x8*)(rdb + lc * 128 + ((16 * lg + 64) ^ swzA));
            bf16x8 a2_0 = *(const bf16x8*)(rdb + 2048 + lc * 128 + ((16 * lg) ^ swzA));
            bf16x8 a2_1 = *(const bf16x8*)(rdb + 2048 + lc * 128 + ((16 * lg + 64) ^ swzA));

            if (!isL2) {
                // prefetch xp for step s+1 (tok[half] = tokens[s+1]) and
                // the token for s+2 into tok[half^1]
                const int tn = tok[half];
                xp[half ^ 1][0] = g_embW[tn * U3 + cz];
                xp[half ^ 1][1] = g_embW[tn * U3 + cr];
                xp[half ^ 1][2] = g_embW[tn * U3 + ch];
                const int s2 = (s + 2 < TT) ? (s + 2) : (TT - 1);
                tok[half ^ 1] = tokens[rowbase + s2];

                if (s < TT) {   // layer 1 computes h1(s)
                    f32x4 az = {bias_z, bias_z, bias_z, bias_z};
                    f32x4 ar = {bias_r, bias_r, bias_r, bias_r};
                    f32x4 ah = {bias_h, bias_h, bias_h, bias_h};
                    az = MFMA16(a1_0, fb[0], az, 0, 0, 0);
                    az = MFMA16(a1_1, fb[1], az, 0, 0, 0);
                    ar = MFMA16(a1_0, fb[2], ar, 0, 0, 0);
                    ar = MFMA16(a1_1, fb[3], ar, 0, 0, 0);
                    ah = MFMA16(a1_0, fb[4], ah, 0, 0, 0);
                    ah = MFMA16(a1_1, fb[5], ah, 0, 0, 0);
                    // gate math: ONLY reg 0 (row 4*lg = this lane's batch row)
                    const float z  = fast_sigmoid(xp[half][0] + az[0]);
                    const float rg = fast_sigmoid(xp[half][1] + ar[0]);
                    const float hh = fast_tanh(xp[half][2] + rg * ah[0]);
                    h1o = z * h1o + (1.0f - z) * hh;
                    *(unsigned short*)(wrb + wbyte) = f2bf(h1o);
                }
            } else {
                if (s > 0) {    // layer 2 computes h2(s-1)
                    f32x4 az = {bias_z,  bias_z,  bias_z,  bias_z };
                    f32x4 ar = {bias_r,  bias_r,  bias_r,  bias_r };
                    f32x4 ax = {bias_h,  bias_h,  bias_h,  bias_h };
                    f32x4 ap = {bias_h2, bias_h2, bias_h2, bias_h2};
                    az = MFMA16(a1_0, fb[0],  az, 0, 0, 0);   // h1@W2 (z)
                    az = MFMA16(a1_1, fb[1],  az, 0, 0, 0);
                    az = MFMA16(a2_0, fb[6],  az, 0, 0, 0);   // + h2@U2 (z)
                    az = MFMA16(a2_1, fb[7],  az, 0, 0, 0);
                    ar = MFMA16(a1_0, fb[2],  ar, 0, 0, 0);
                    ar = MFMA16(a1_1, fb[3],  ar, 0, 0, 0);
                    ar = MFMA16(a2_0, fb[8],  ar, 0, 0, 0);
                    ar = MFMA16(a2_1, fb[9],  ar, 0, 0, 0);
                    ax = MFMA16(a1_0, fb[4],  ax, 0, 0, 0);   // xh (input side)
                    ax = MFMA16(a1_1, fb[5],  ax, 0, 0, 0);
                    ap = MFMA16(a2_0, fb[10], ap, 0, 0, 0);   // hph (recurrent)
                    ap = MFMA16(a2_1, fb[11], ap, 0, 0, 0);
                    // gate math: ONLY reg 0
                    const float z  = fast_sigmoid(az[0]);
                    const float rg = fast_sigmoid(ar[0]);
                    const float hh = fast_tanh(ax[0] + rg * ap[0]);
                    h2o = z * h2o + (1.0f - z) * hh;
                    *(unsigned short*)(wrb + 2048 + wbyte) = f2bf(h2o);
                }
            }
            __syncthreads();
        }
    }

    // ---- output head: h2(TT-1) sits in buf0/which=1 (step TT wrote buf0).
    // Lane j (0..3) of wave 0 handles batch row j at LDS row 4*j.
    if (wave == 0 && lane < BPB) {
        const int row = 4 * lane;
        float acc = bout[0];
        #pragma unroll 8
        for (int u = 0; u < UU; ++u) {
            const unsigned short hv = *(const unsigned short*)(hls + 2048 +
                row * 128 + ((u * 2) ^ ((row & 7) << 4)));
            acc = fmaf(bf2f(hv), Wout[u], acc);
        }
        out[blk * BPB + lane] = fast_sigmoid(acc);
    }
}

extern "C" void kernel_launch(void* const* d_in, const int* in_sizes, int n_in,
                              void* d_out, int out_size, void* d_ws, size_t ws_size,
                              hipStream_t stream) {
    const int*   tokens = (const int*)  d_in[0];
    const float* emb    = (const float*)d_in[1];
    const float* W1     = (const float*)d_in[2];
    const float* U1w    = (const float*)d_in[3];
    const float* b1     = (const float*)d_in[4];
    const float* W2     = (const float*)d_in[5];
    const float* U2w    = (const float*)d_in[6];
    const float* b2     = (const float*)d_in[7];
    const float* Wout   = (const float*)d_in[8];
    const float* bout   = (const float*)d_in[9];
    float* out = (float*)d_out;

    gru_embw_kernel<<<VV, 192, 0, stream>>>(emb, W1, b1);
    gru_scan_kernel<<<NBLK, 512, 0, stream>>>(tokens, U1w, b1, W2, U2w,
                                              b2, Wout, bout, out);
}